// Round 13
// baseline (2248.202 us; speedup 1.0000x reference)
//
#include <hip/hip_runtime.h>
#include <hip/hip_bf16.h>

typedef unsigned short ushort_t;
typedef __attribute__((ext_vector_type(8))) short short8_t;
typedef __attribute__((ext_vector_type(4))) float f32x4;
typedef __attribute__((ext_vector_type(4))) unsigned uint4_t;

#define NLIG 5000
#define NREC 15000
#define NTOT 20000
#define ELIG 50000
#define EREC 150000
#define ETOT 200000
#define VSTRIDE 20160
#define NB0 313   // (NLIG+15)/16
#define NB1 938   // (NREC+15)/16

// ---------- helpers ----------
__device__ __forceinline__ float us2f(ushort_t u){
  union { float f; unsigned int i; } x; x.i = ((unsigned int)u) << 16; return x.f;
}
__device__ __forceinline__ ushort_t f2us(float f){
  __hip_bfloat16 b = __float2bfloat16(f);
  return *reinterpret_cast<ushort_t*>(&b);
}
__device__ __forceinline__ unsigned pkbf(float a, float b){
  return (unsigned)f2us(a) | ((unsigned)f2us(b) << 16);
}
__device__ __forceinline__ float wsum64(float v){
#pragma unroll
  for (int s = 32; s >= 1; s >>= 1) v += __shfl_xor(v, s, 64);
  return v;
}
__device__ __forceinline__ f32x4 mfma32(short8_t a, short8_t b, f32x4 c){
  return __builtin_amdgcn_mfma_f32_16x16x32_bf16(a, b, c, 0, 0, 0);
}
__device__ __forceinline__ int geti(const int* __restrict__ p, int i, int i64){
  return i64 ? p[2*i] : p[i];
}

// ---------- dtype detection ----------
__global__ void kdetect2(const unsigned* __restrict__ xw, const unsigned* __restrict__ iw,
                         int* __restrict__ flagp){
  const int lane = threadIdx.x;
  unsigned w = xw[lane];
  int e0 = (int)((w >> 7) & 0xFF);
  int hit = (e0 >= 100 && e0 <= 134) ? 1 : 0;
  int zodd = ((lane & 1) && iw[lane] == 0u) ? 1 : 0;
#pragma unroll
  for (int s = 32; s >= 1; s >>= 1){
    hit  += __shfl_xor(hit,  s, 64);
    zodd += __shfl_xor(zodd, s, 64);
  }
  if (lane == 0){
    flagp[0] = (hit  >= 40) ? 1 : 0;
    flagp[1] = (zodd >= 24) ? 1 : 0;
  }
}

__global__ void ksent(float* __restrict__ out, int n, float c){
  int i = blockIdx.x*256 + threadIdx.x;
  if (i < n) out[i] = c;
}

// ---------- input conversion ----------
__global__ void kcvt_x(const void* __restrict__ lx, const void* __restrict__ rx,
                       const int* __restrict__ flagp, float* __restrict__ xall){
  const int flag = flagp[0];
  const int idx = blockIdx.x*256 + threadIdx.x;
  const void* src; int local;
  if (idx < NLIG*64){ src = lx; local = idx; } else { src = rx; local = idx - NLIG*64; }
  float v;
  if (flag) v = us2f(((const ushort_t*)src)[local]);
  else      v = ((const float*)src)[local];
  xall[idx] = v;
}

struct Srcs { const void* p[20]; };
__global__ void kcvt_w(Srcs S, const int* __restrict__ flagp, float* __restrict__ wcvt){
  const int bounds[21] = {0,4096,4160,5184,5248,267392,271488,275584,275648,283840,
                          283904,288000,292096,296192,300288,304384,308480,308544,308608,308672,308736};
  const int flag = flagp[0];
  const int idx = blockIdx.x*256 + threadIdx.x;
  if (idx >= 308736) return;
  int seg = 0;
#pragma unroll
  for (int s = 1; s < 20; ++s) if (idx >= bounds[s]) seg = s;
  const void* src = S.p[0];
#pragma unroll
  for (int s = 1; s < 20; ++s) if (seg == s) src = S.p[s];
  const int local = idx - bounds[seg];
  float v;
  if (flag) v = us2f(((const ushort_t*)src)[local]);
  else      v = ((const float*)src)[local];
  wcvt[idx] = v;
}

#define W_W0    0
#define W_B0    4096
#define W_WE1   4160
#define W_BE1   5184
#define W_WE2   5248
#define W_BE2   267392
#define W_RESW  271488
#define W_CONVB 275584
#define W_MSGW  275648
#define W_MSGB  283840
#define W_QLIG  283904
#define W_KLIG  288000
#define W_VLIG  292096
#define W_QREC  296192
#define W_KREC  300288
#define W_VREC  304384
#define W_GLIG  308480
#define W_BLIG  308544
#define W_GREC  308608
#define W_BREC  308672

// Fragment-packed We2: Wpk[((kb*4+t)*2+p)*512 + lane*8 + j]
__global__ void kWpk(const float* __restrict__ We2f, ushort_t* __restrict__ Wpk){
  int oidx = blockIdx.x*256 + threadIdx.x;   // 524288 exact (grid 2048)
  int j = oidx & 7, lane = (oidx >> 3) & 63, p = (oidx >> 9) & 1;
  int t = (oidx >> 10) & 3, kb = oidx >> 12;
  int o = t*16 + (lane & 15);
  int gik = kb*32 + (lane >> 4)*8 + j;
  int i = gik >> 6, k = gik & 63;
  float v = We2f[(size_t)(i*64 + o)*64 + k];
  ushort_t hi = f2us(v);
  Wpk[oidx] = p ? f2us(v - us2f(hi)) : hi;
}

// h0 = relu(x @ W0^T + b0), f32
__global__ void kh0(const float* __restrict__ xall, const float* __restrict__ W0f,
                    const float* __restrict__ b0f, float* __restrict__ h){
  __shared__ float xr[4][64];
  const int lane = threadIdx.x & 63, wv = threadIdx.x >> 6;
  const int n = blockIdx.x*4 + wv;
  xr[wv][lane] = xall[(size_t)n*64 + lane];
  __syncthreads();
  float acc = b0f[lane];
  const float* wr = W0f + lane*64;
#pragma unroll
  for (int i = 0; i < 64; ++i) acc += xr[wv][i] * wr[i];
  h[(size_t)n*64 + lane] = acc > 0.f ? acc : 0.f;
}

__global__ void khist(const int* __restrict__ ldst, const int* __restrict__ rdst,
                      const int* __restrict__ flagp, int* __restrict__ counts){
  const int i64 = flagp[1];
  const int e = blockIdx.x*256 + threadIdx.x;
  if (e >= ETOT) return;
  int dstg = (e < ELIG) ? geti(ldst, e, i64) : geti(rdst, e - ELIG, i64) + NLIG;
  atomicAdd(&counts[dstg], 1);
}

__global__ __launch_bounds__(1024) void kscan(const int* __restrict__ counts, int* __restrict__ offs){
  __shared__ int part[1024];
  const int tid = threadIdx.x;
  const int PER = 20;
  int loc[PER]; int s = 0;
#pragma unroll
  for (int j = 0; j < PER; ++j){ int idx = tid*PER + j; int v = (idx < NTOT) ? counts[idx] : 0; loc[j] = s; s += v; }
  part[tid] = s;
  __syncthreads();
  for (int d = 1; d < 1024; d <<= 1){
    int add = (tid >= d) ? part[tid - d] : 0;
    __syncthreads();
    part[tid] += add;
    __syncthreads();
  }
  int pre = (tid > 0) ? part[tid - 1] : 0;
#pragma unroll
  for (int j = 0; j < PER; ++j){ int idx = tid*PER + j; if (idx < NTOT) offs[idx] = pre + loc[j]; }
  if (tid == 1023) offs[NTOT] = part[1023];
}

__global__ void kfill(const int* __restrict__ lsrc, const int* __restrict__ ldst,
                      const int* __restrict__ rsrc, const int* __restrict__ rdst,
                      const void* __restrict__ lef, const void* __restrict__ ref_,
                      const int* __restrict__ offs, int* __restrict__ cursor,
                      const int* __restrict__ flagp,
                      int* __restrict__ e_srcn, float* __restrict__ ef_srt){
  const int flag = flagp[0];
  const int i64  = flagp[1];
  const int e = blockIdx.x*256 + threadIdx.x;
  if (e >= ETOT) return;
  int srcg, dstg, le; const void* efb;
  if (e < ELIG){ srcg = geti(lsrc, e, i64); dstg = geti(ldst, e, i64); efb = lef; le = e; }
  else {
    int e2 = e - ELIG;
    srcg = geti(rsrc, e2, i64) + NLIG; dstg = geti(rdst, e2, i64) + NLIG; efb = ref_; le = e2;
  }
  int pos = offs[dstg] + atomicAdd(&cursor[dstg], 1);
  e_srcn[pos] = srcg;
  float* efd = ef_srt + (size_t)pos*16;
  if (flag){
    const ushort_t* efp = (const ushort_t*)efb + (size_t)le*16;
#pragma unroll
    for (int c = 0; c < 16; ++c) efd[c] = us2f(efp[c]);
  } else {
    const float* efp = (const float*)efb + (size_t)le*16;
#pragma unroll
    for (int c = 0; c < 16; ++c) efd[c] = efp[c];
  }
}

// ---------- fused message-passing step: 16 nodes/WG, 16 waves, packed-B MFMA ----------
// S tile rows padded to 2080 B (was 2048 + XOR): A-frag ds_read_b128 drops 8-way -> 4-way.
#define SROW 2080
#define SLO  (16*SROW)
__global__ __launch_bounds__(1024)
void kstep(const float* __restrict__ hin, float* __restrict__ hout,
           const int* __restrict__ offs, const int* __restrict__ e_srcn,
           const float* __restrict__ ef_srt,
           const ushort_t* __restrict__ Wpk,
           const float* __restrict__ We1f, const float* __restrict__ be1f,
           const float* __restrict__ resWf, const float* __restrict__ convbf,
           const float* __restrict__ msgWf, const float* __restrict__ msgbf,
           const float* __restrict__ be2f){
  __shared__ alignas(16) char sbuf[2*SLO];   // 66560 B; epilogue overlays
  __shared__ float h_lds[1024];
  __shared__ float Hs_lds[1024];
  __shared__ float m_lds[1024];
  __shared__ float cbf[64], mbf[64];

  const int tid = threadIdx.x, lane = tid & 63, wv = tid >> 6;
  const int n0 = blockIdx.x * 16;            // grid = NTOT/16 = 1250 exact

  h_lds[tid] = hin[(size_t)n0*64 + tid];
  if (tid < 64){ cbf[tid] = convbf[tid]; mbf[tid] = msgbf[tid]; }

  float w1r[16];
#pragma unroll
  for (int c = 0; c < 16; ++c) w1r[c] = We1f[lane*16 + c];
  const float b1 = be1f[lane];

  // phase 1
  float sacc[64];
#pragma unroll
  for (int i = 0; i < 64; ++i) sacc[i] = 0.f;
  float hs = 0.f;
  {
    const int v = n0 + wv;
    const int jb = offs[v], je = offs[v+1];
    for (int j = jb; j < je; ++j){
      const int sn = e_srcn[j];
      const float* efp = ef_srt + (size_t)j*16;
      float zl = b1;
#pragma unroll
      for (int c = 0; c < 16; ++c) zl += efp[c] * w1r[c];
      zl = zl > 0.f ? zl : 0.f;
      hs += hin[(size_t)sn*64 + lane];
      const float4* hp = (const float4*)(hin + (size_t)sn*64);
#pragma unroll
      for (int i4 = 0; i4 < 16; ++i4){
        float4 hv = hp[i4];
        sacc[i4*4+0] += hv.x * zl;
        sacc[i4*4+1] += hv.y * zl;
        sacc[i4*4+2] += hv.z * zl;
        sacc[i4*4+3] += hv.w * zl;
      }
    }
    Hs_lds[wv*64 + lane] = hs;
  }

  // phase 2
  const int r15 = lane & 15, g4 = lane >> 4;
  const int tW = wv & 3, kq = wv >> 2;
  f32x4 acc; acc[0]=0.f; acc[1]=0.f; acc[2]=0.f; acc[3]=0.f;
#pragma unroll
  for (int c = 0; c < 4; ++c){
#pragma unroll
    for (int ii = 0; ii < 16; ++ii){
      float v = sacc[c*16 + ii];
      ushort_t hi16 = f2us(v);
      unsigned off = (unsigned)(wv*SROW + (ii*64 + lane)*2);
      *(ushort_t*)(sbuf + off) = hi16;
      *(ushort_t*)(sbuf + SLO + off) = f2us(v - us2f(hi16));
    }
    __syncthreads();
    for (int kk = 0; kk < 8; ++kk){
      const int lk = kq*256 + kk*32;
      const int kb = c*32 + kq*8 + kk;
      const unsigned aoff = (unsigned)(r15*SROW + (lk + g4*8)*2);
      const short8_t ah = *(const short8_t*)(sbuf + aoff);
      const short8_t al = *(const short8_t*)(sbuf + SLO + aoff);
      const ushort_t* bp = Wpk + (size_t)(kb*4 + tW)*1024 + lane*8;
      const short8_t bh = *(const short8_t*)(bp);
      const short8_t bl = *(const short8_t*)(bp + 512);
      acc = mfma32(ah, bh, acc);
      acc = mfma32(ah, bl, acc);
      acc = mfma32(al, bh, acc);
    }
    __syncthreads();
  }

  // epilogue
  float* redf  = (float*)sbuf;
  float* be2s  = (float*)(sbuf + 16384);
  float* resWt = (float*)(sbuf + 32768);
#pragma unroll
  for (int q = 0; q < 4; ++q)
    redf[kq*1024 + (g4*4 + q)*64 + tW*16 + r15] = acc[q];
  for (int idx = tid; idx < 4096; idx += 1024){
    be2s[idx] = be2f[idx];
    resWt[(idx & 63)*65 + (idx >> 6)] = resWf[idx];
  }
  __syncthreads();
  {
    float aggv = cbf[lane];
#pragma unroll
    for (int k4 = 0; k4 < 4; ++k4) aggv += redf[k4*1024 + wv*64 + lane];
    float t1 = 0.f, t2 = 0.f;
#pragma unroll 8
    for (int i = 0; i < 64; ++i){
      t1 += Hs_lds[wv*64 + i] * be2s[i*64 + lane];
      t2 += h_lds[wv*64 + i]  * resWt[i*65 + lane];
    }
    float mv = aggv + t1 + t2;
    m_lds[wv*64 + lane] = mv > 0.f ? mv : 0.f;
  }
  __syncthreads();
  float* msgWt = (float*)sbuf;
  for (int idx = tid; idx < 8192; idx += 1024)
    msgWt[(idx & 127)*65 + (idx >> 7)] = msgWf[idx];
  __syncthreads();
  {
    float hn = mbf[lane];
#pragma unroll 8
    for (int i = 0; i < 64; ++i){
      hn += m_lds[wv*64 + i] * msgWt[i*65 + lane];
      hn += h_lds[wv*64 + i] * msgWt[(64 + i)*65 + lane];
    }
    hout[(size_t)(n0 + wv)*64 + lane] = hn;
  }
}

// ---------- Fv residual + mid-LN + q/k/v projections (q,k hi/lo bf16; V transposed) ----------
__global__ void kfvproj(const float* __restrict__ h, const float* __restrict__ xall,
    const float* __restrict__ wcvt,
    ushort_t* __restrict__ qbh, ushort_t* __restrict__ qbl,
    ushort_t* __restrict__ kbh, ushort_t* __restrict__ kbl,
    ushort_t* __restrict__ vbT){
  __shared__ float hr[4][64];
  const int lane = threadIdx.x & 63, wv = threadIdx.x >> 6;
  const int n = blockIdx.x*4 + wv;
  const bool isLig = n < NLIG;
  const float fv = h[(size_t)n*64 + lane] + xall[(size_t)n*64 + lane];
  const float mu = wsum64(fv) * (1.f/64.f);
  const float dd = fv - mu;
  const float var = wsum64(dd*dd) * (1.f/64.f);
  const float gg = wcvt[(isLig ? W_GLIG : W_GREC) + lane];
  const float bb = wcvt[(isLig ? W_BLIG : W_BREC) + lane];
  const float hl = dd * rsqrtf(var + 1e-5f) * gg + bb;
  hr[wv][lane] = hl;
  __syncthreads();
  const float* Qw = wcvt + (isLig ? W_QLIG : W_QREC) + lane*64;
  const float* Kw = wcvt + (isLig ? W_KLIG : W_KREC) + lane*64;
  const float* Vw = wcvt + (isLig ? W_VLIG : W_VREC) + lane*64;
  float qa = 0.f, ka = 0.f, va = 0.f;
#pragma unroll
  for (int i = 0; i < 64; ++i){
    const float hv = hr[wv][i];
    qa += hv * Qw[i];
    ka += hv * Kw[i];
    va += hv * Vw[i];
  }
  qa = qa > 0.f ? qa : 0.01f*qa;
  ka = ka > 0.f ? ka : 0.01f*ka;
  const size_t o = (size_t)n*64 + lane;
  ushort_t qh = f2us(qa); qbh[o] = qh; qbl[o] = f2us(qa - us2f(qh));
  ushort_t kh = f2us(ka); kbh[o] = kh; kbl[o] = f2us(ka - us2f(kh));
  vbT[(size_t)lane*VSTRIDE + n] = f2us(va);
}

// ---------- merged masked cross-attention + final LN (both dirs, TILE=512, 2-deep prefetch) ----------
__global__ __launch_bounds__(512)
void kattn2(const ushort_t* __restrict__ qbh, const ushort_t* __restrict__ qbl,
            const ushort_t* __restrict__ kbh, const ushort_t* __restrict__ kbl,
            const ushort_t* __restrict__ vbT, const void* __restrict__ maskp,
            const int* __restrict__ flagp, const float* __restrict__ wcvt,
            float* __restrict__ out){
  __shared__ alignas(16) char abuf[65664];   // union: m_tile[2][16][513] f32 | ored[8][64][17] f32
  __shared__ float mred[8][16], lred[8][16];
  float (*m_tile)[16][513] = (float(*)[16][513])abuf;
  float (*ored)[64][17]    = (float(*)[64][17])abuf;

  const int flag = flagp[0];
  const int bx = blockIdx.x;
  const int dirn = (bx < NB0) ? 0 : 1;
  const int bid  = dirn ? (bx - NB0) : bx;
  const int R   = dirn ? NREC : NLIG;
  const int C   = dirn ? NLIG : NREC;
  const int RNB = dirn ? NLIG : 0;
  const int CNB = dirn ? 0 : NLIG;
  const float* gwf = wcvt + (dirn ? W_GREC : W_GLIG);
  const float* bwf = wcvt + (dirn ? W_BREC : W_BLIG);
  float* outp = out + (size_t)RNB*64;

  const int tid = threadIdx.x, lane = tid & 63, wv = tid >> 6;
  const int r15 = lane & 15, g4 = lane >> 4;
  const int rbase = bid * 16;
  int rn = rbase + r15; if (rn > R-1) rn = R-1;

  const ushort_t* qph = qbh + (size_t)(RNB + rn)*64;
  const ushort_t* qpl = qbl + (size_t)(RNB + rn)*64;
  const short8_t qh0a = *(const short8_t*)(qph + g4*8);
  const short8_t qh0b = *(const short8_t*)(qph + 32 + g4*8);
  const short8_t ql0a = *(const short8_t*)(qpl + g4*8);
  const short8_t ql0b = *(const short8_t*)(qpl + 32 + g4*8);

  const int srcA = (((g4 & 1) * 2)     << 4) + r15;
  const int srcB = (((g4 & 1) * 2 + 1) << 4) + r15;
  const bool hiBank = (g4 >> 1) != 0;

  const int s_row = tid >> 5, s_l31 = tid & 31;   // dirn0 staging

  float mrun = -1e30f, lrun = 0.f;
  f32x4 oacc[4];
#pragma unroll
  for (int t = 0; t < 4; ++t){ oacc[t][0]=0.f; oacc[t][1]=0.f; oacc[t][2]=0.f; oacc[t][3]=0.f; }

  auto load_tile = [&](int tb2, float (&mr)[16]){
    if (dirn == 0){
      int r = rbase + s_row; if (r > R-1) r = R-1;
      const size_t base = (size_t)r*NREC + tb2;
      const int cmax = C-1 - tb2;
      if (flag){
        const ushort_t* mp = (const ushort_t*)maskp + base;
#pragma unroll
        for (int j = 0; j < 16; ++j){
          int cj = s_l31 + 32*j; if (cj > cmax) cj = cmax;
          mr[j] = us2f(mp[cj]);
        }
      } else {
        const float* mp = (const float*)maskp + base;
#pragma unroll
        for (int j = 0; j < 16; ++j){
          int cj = s_l31 + 32*j; if (cj > cmax) cj = cmax;
          mr[j] = mp[cj];
        }
      }
    } else {
      int c = tb2 + tid; if (c > C-1) c = C-1;
      const size_t base = (size_t)c*NREC + rbase;
      if (rbase + 16 <= R){
        if (flag){
          const ushort_t* mp = (const ushort_t*)maskp + base;
          const short8_t v0 = *(const short8_t*)mp;
          const short8_t v1 = *(const short8_t*)(mp + 8);
#pragma unroll
          for (int j = 0; j < 8; ++j){ mr[j] = us2f((ushort_t)v0[j]); mr[8+j] = us2f((ushort_t)v1[j]); }
        } else {
          const float* mp = (const float*)maskp + base;
#pragma unroll
          for (int q = 0; q < 4; ++q){
            const float4 v = *(const float4*)(mp + q*4);
            mr[q*4+0]=v.x; mr[q*4+1]=v.y; mr[q*4+2]=v.z; mr[q*4+3]=v.w;
          }
        }
      } else {
        // last partial row-block: per-row clamp (uniform branch)
#pragma unroll
        for (int j = 0; j < 16; ++j){
          int r = rbase + j; if (r > R-1) r = R-1;
          const size_t mo = (size_t)c*NREC + r;
          mr[j] = flag ? us2f(((const ushort_t*)maskp)[mo]) : ((const float*)maskp)[mo];
        }
      }
    }
  };

  auto stage_write = [&](const float (&mr)[16], int bufc){
    if (dirn == 0){
#pragma unroll
      for (int j = 0; j < 16; ++j) m_tile[bufc][s_row][s_l31 + 32*j] = mr[j];
    } else {
#pragma unroll
      for (int j = 0; j < 16; ++j) m_tile[bufc][j][tid] = mr[j];
    }
  };

  auto compute = [&](int tb, int bufc){
#pragma unroll
    for (int sub = 0; sub < 2; ++sub){
      const int cb = tb + wv*64 + sub*32;
      const int mb = wv*64 + sub*32;
      int cn0 = cb + r15;      if (cn0 > C-1) cn0 = C-1;
      int cn1 = cb + 16 + r15; if (cn1 > C-1) cn1 = C-1;
      const ushort_t* kp0h = kbh + (size_t)(CNB + cn0)*64;
      const ushort_t* kp0l = kbl + (size_t)(CNB + cn0)*64;
      const ushort_t* kp1h = kbh + (size_t)(CNB + cn1)*64;
      const ushort_t* kp1l = kbl + (size_t)(CNB + cn1)*64;
      f32x4 st0; st0[0]=0.f; st0[1]=0.f; st0[2]=0.f; st0[3]=0.f;
      f32x4 st1 = st0;
      {
        short8_t ka_ = *(const short8_t*)(kp0h + g4*8);
        short8_t kb_ = *(const short8_t*)(kp0h + 32 + g4*8);
        st0 = mfma32(ka_, qh0a, st0); st0 = mfma32(kb_, qh0b, st0);
        st0 = mfma32(ka_, ql0a, st0); st0 = mfma32(kb_, ql0b, st0);
        short8_t kc_ = *(const short8_t*)(kp0l + g4*8);
        short8_t kd_ = *(const short8_t*)(kp0l + 32 + g4*8);
        st0 = mfma32(kc_, qh0a, st0); st0 = mfma32(kd_, qh0b, st0);
      }
      {
        short8_t ka_ = *(const short8_t*)(kp1h + g4*8);
        short8_t kb_ = *(const short8_t*)(kp1h + 32 + g4*8);
        st1 = mfma32(ka_, qh0a, st1); st1 = mfma32(kb_, qh0b, st1);
        st1 = mfma32(ka_, ql0a, st1); st1 = mfma32(kb_, ql0b, st1);
        short8_t kc_ = *(const short8_t*)(kp1l + g4*8);
        short8_t kd_ = *(const short8_t*)(kp1l + 32 + g4*8);
        st1 = mfma32(kc_, qh0a, st1); st1 = mfma32(kd_, qh0b, st1);
      }
      float sv0[4], sv1[4]; float tmax = -1e30f;
#pragma unroll
      for (int j = 0; j < 4; ++j){
        const int c0 = cb + g4*4 + j, c1 = cb + 16 + g4*4 + j;
        const float mv0 = m_tile[bufc][r15][mb + g4*4 + j];
        const float mv1 = m_tile[bufc][r15][mb + 16 + g4*4 + j];
        sv0[j] = (c0 < C) ? mv0 * (st0[j] + 1000.f) : -1e30f;
        sv1[j] = (c1 < C) ? mv1 * (st1[j] + 1000.f) : -1e30f;
        tmax = fmaxf(tmax, fmaxf(sv0[j], sv1[j]));
      }
      tmax = fmaxf(tmax, __shfl_xor(tmax, 16, 64));
      tmax = fmaxf(tmax, __shfl_xor(tmax, 32, 64));
      const float mnew = fmaxf(mrun, tmax);
      const float corr = __expf(mrun - mnew);
      float ps0[4], ps1[4], psum = 0.f;
#pragma unroll
      for (int j = 0; j < 4; ++j){
        ps0[j] = __expf(sv0[j] - mnew); psum += ps0[j];
        ps1[j] = __expf(sv1[j] - mnew); psum += ps1[j];
      }
      psum += __shfl_xor(psum, 16, 64);
      psum += __shfl_xor(psum, 32, 64);
      lrun = lrun * corr + psum;
      mrun = mnew;
      const unsigned pk0 = pkbf(ps0[0], ps0[1]);
      const unsigned pk1 = pkbf(ps0[2], ps0[3]);
      const unsigned pk2 = pkbf(ps1[0], ps1[1]);
      const unsigned pk3 = pkbf(ps1[2], ps1[3]);
      const unsigned a0 = (unsigned)__shfl((int)pk0, srcA, 64);
      const unsigned a2 = (unsigned)__shfl((int)pk2, srcA, 64);
      const unsigned a1 = (unsigned)__shfl((int)pk1, srcA, 64);
      const unsigned a3 = (unsigned)__shfl((int)pk3, srcA, 64);
      const unsigned b0 = (unsigned)__shfl((int)pk0, srcB, 64);
      const unsigned b2 = (unsigned)__shfl((int)pk2, srcB, 64);
      const unsigned b1 = (unsigned)__shfl((int)pk1, srcB, 64);
      const unsigned b3 = (unsigned)__shfl((int)pk3, srcB, 64);
      uint4_t pw;
      pw[0] = hiBank ? a2 : a0;
      pw[1] = hiBank ? a3 : a1;
      pw[2] = hiBank ? b2 : b0;
      pw[3] = hiBank ? b3 : b1;
      const short8_t pf8 = *reinterpret_cast<const short8_t*>(&pw);
      const ushort_t* vtb = vbT + (size_t)(CNB + cb + g4*8);
#pragma unroll
      for (int t = 0; t < 4; ++t){
#pragma unroll
        for (int q = 0; q < 4; ++q) oacc[t][q] *= corr;
        const short8_t af = *(const short8_t*)(vtb + (size_t)(t*16 + r15)*VSTRIDE);
        oacc[t] = mfma32(af, pf8, oacc[t]);
      }
    }
  };

  const int nt = (C + 511) >> 9;     // 30 (dirn0) / 10 (dirn1), both even
  float mrA[16], mrB[16];
  load_tile(0, mrA);
  if (nt > 1) load_tile(512, mrB);
  for (int t = 0; t < nt; t += 2){
    stage_write(mrA, 0);
    if (t + 2 < nt) load_tile((t + 2) << 9, mrA);
    __syncthreads();
    compute(t << 9, 0);
    if (t + 1 < nt){
      stage_write(mrB, 1);
      if (t + 3 < nt) load_tile((t + 3) << 9, mrB);
      __syncthreads();
      compute((t + 1) << 9, 1);
    }
  }

  __syncthreads();   // all m_tile reads done before ored overlay writes
  if (g4 == 0){ mred[wv][r15] = mrun; lred[wv][r15] = lrun; }
#pragma unroll
  for (int t = 0; t < 4; ++t)
#pragma unroll
    for (int q = 0; q < 4; ++q)
      ored[wv][t*16 + g4*4 + q][r15] = oacc[t][q];
  __syncthreads();

  for (int rr = 2*wv; rr <= 2*wv + 1; ++rr){
    float mstar = -1e30f;
#pragma unroll
    for (int w = 0; w < 8; ++w) mstar = fmaxf(mstar, mred[w][rr]);
    float lstar = 0.f, ov = 0.f;
#pragma unroll
    for (int w = 0; w < 8; ++w){
      const float e = __expf(mred[w][rr] - mstar);
      lstar += lred[w][rr] * e;
      ov    += ored[w][lane][rr] * e;
    }
    const float att = ov / lstar;
    const float mu = wsum64(att) * (1.f/64.f);
    const float dd = att - mu;
    const float var = wsum64(dd*dd) * (1.f/64.f);
    const float y = dd * rsqrtf(var + 1e-5f) * gwf[lane] + bwf[lane];
    const int rg = rbase + rr;
    if (rg < R) outp[(size_t)rg*64 + lane] = y;
  }
}

// ---------- host ----------
extern "C" void kernel_launch(void* const* d_in, const int* in_sizes, int n_in,
                              void* d_out, int out_size, void* d_ws, size_t ws_size,
                              hipStream_t stream){
  const int expsz[29] = {320000,800000,50000,50000,960000,2400000,150000,150000,75000000,
                         4096,64,1024,64,262144,4096,4096,64,8192,64,
                         4096,4096,4096,4096,4096,4096,64,64,64,64};
  bool ok = (n_in == 29);
  if (ok) for (int i = 0; i < 29; ++i) if (in_sizes[i] != expsz[i]) ok = false;
  if (!ok){
    ksent<<<(out_size + 255)/256, 256, 0, stream>>>((float*)d_out, out_size, 10.0f);
    return;
  }

  const void* lig_n = d_in[0];
  const void* lig_e = d_in[1];
  const int* lig_src = (const int*)d_in[2];
  const int* lig_dst = (const int*)d_in[3];
  const void* rec_n = d_in[4];
  const void* rec_e = d_in[5];
  const int* rec_src = (const int*)d_in[6];
  const int* rec_dst = (const int*)d_in[7];
  const void* mask = d_in[8];

  char* p = (char*)d_ws;
  auto carve = [&](size_t bytes)->char*{ char* r = p; p += (bytes + 255) & ~(size_t)255; return r; };
  float*    xall  = (float*)   carve((size_t)NTOT*64*4);
  float*    wcvt  = (float*)   carve((size_t)308736*4);
  float*    h_a   = (float*)   carve((size_t)NTOT*64*4);
  float*    h_b   = (float*)   carve((size_t)NTOT*64*4);
  ushort_t* Wpk   = (ushort_t*)carve((size_t)524288*2);
  ushort_t* qbh   = (ushort_t*)carve((size_t)NTOT*64*2);
  ushort_t* qbl   = (ushort_t*)carve((size_t)NTOT*64*2);
  ushort_t* kbh   = (ushort_t*)carve((size_t)NTOT*64*2);
  ushort_t* kbl   = (ushort_t*)carve((size_t)NTOT*64*2);
  ushort_t* vbT   = (ushort_t*)carve((size_t)64*VSTRIDE*2);
  int*      flag  = (int*)     carve(256);
  int*      counts= (int*)     carve((size_t)2*NTOT*4);
  int*      cursor= counts + NTOT;
  int*      offs  = (int*)     carve((size_t)(NTOT+1)*4);
  int*      e_srcn= (int*)     carve((size_t)ETOT*4);
  float*    ef_srt= (float*)   carve((size_t)ETOT*16*4);

  if ((size_t)(p - (char*)d_ws) > ws_size){
    ksent<<<(out_size + 255)/256, 256, 0, stream>>>((float*)d_out, out_size, 20.0f);
    return;
  }

  Srcs S;
  for (int i = 0; i < 20; ++i) S.p[i] = d_in[9 + i];

  hipMemsetAsync(counts, 0, (size_t)2*NTOT*4, stream);
  hipMemsetAsync(vbT, 0, (size_t)64*VSTRIDE*2, stream);
  kdetect2<<<1, 64, 0, stream>>>((const unsigned*)lig_n, (const unsigned*)lig_src, flag);
  kcvt_x<<<NTOT*64/256, 256, 0, stream>>>(lig_n, rec_n, flag, xall);
  kcvt_w<<<(308736 + 255)/256, 256, 0, stream>>>(S, flag, wcvt);
  kWpk<<<2048, 256, 0, stream>>>(wcvt + W_WE2, Wpk);
  kh0<<<NTOT/4, 256, 0, stream>>>(xall, wcvt + W_W0, wcvt + W_B0, h_a);
  khist<<<(ETOT + 255)/256, 256, 0, stream>>>(lig_dst, rec_dst, flag, counts);
  kscan<<<1, 1024, 0, stream>>>(counts, offs);
  kfill<<<(ETOT + 255)/256, 256, 0, stream>>>(lig_src, lig_dst, rec_src, rec_dst,
                                              lig_e, rec_e, offs, cursor, flag, e_srcn, ef_srt);
  float* hi = h_a; float* ho = h_b;
  for (int s = 0; s < 6; ++s){
    kstep<<<NTOT/16, 1024, 0, stream>>>(hi, ho, offs, e_srcn, ef_srt, Wpk,
                                        wcvt + W_WE1, wcvt + W_BE1, wcvt + W_RESW,
                                        wcvt + W_CONVB, wcvt + W_MSGW, wcvt + W_MSGB,
                                        wcvt + W_BE2);
    float* t = hi; hi = ho; ho = t;
  }
  kfvproj<<<NTOT/4, 256, 0, stream>>>(hi, xall, wcvt, qbh, qbl, kbh, kbl, vbT);
  kattn2<<<NB0 + NB1, 512, 0, stream>>>(qbh, qbl, kbh, kbl, vbT, mask, flag, wcvt,
                                        (float*)d_out);
}

// Round 14
// 2111.735 us; speedup vs baseline: 1.0646x; 1.0646x over previous
//
#include <hip/hip_runtime.h>
#include <hip/hip_bf16.h>

typedef unsigned short ushort_t;
typedef __attribute__((ext_vector_type(8))) short short8_t;
typedef __attribute__((ext_vector_type(4))) float f32x4;
typedef __attribute__((ext_vector_type(4))) unsigned uint4_t;

#define NLIG 5000
#define NREC 15000
#define NTOT 20000
#define ELIG 50000
#define EREC 150000
#define ETOT 200000
#define VSTRIDE 20160
#define NB0 313   // (NLIG+15)/16
#define NB1 938   // (NREC+15)/16

// ---------- helpers ----------
__device__ __forceinline__ float us2f(ushort_t u){
  union { float f; unsigned int i; } x; x.i = ((unsigned int)u) << 16; return x.f;
}
__device__ __forceinline__ ushort_t f2us(float f){
  __hip_bfloat16 b = __float2bfloat16(f);
  return *reinterpret_cast<ushort_t*>(&b);
}
__device__ __forceinline__ unsigned pkbf(float a, float b){
  return (unsigned)f2us(a) | ((unsigned)f2us(b) << 16);
}
__device__ __forceinline__ float wsum64(float v){
#pragma unroll
  for (int s = 32; s >= 1; s >>= 1) v += __shfl_xor(v, s, 64);
  return v;
}
__device__ __forceinline__ f32x4 mfma32(short8_t a, short8_t b, f32x4 c){
  return __builtin_amdgcn_mfma_f32_16x16x32_bf16(a, b, c, 0, 0, 0);
}
__device__ __forceinline__ int geti(const int* __restrict__ p, int i, int i64){
  return i64 ? p[2*i] : p[i];
}

// ---------- dtype detection ----------
__global__ void kdetect2(const unsigned* __restrict__ xw, const unsigned* __restrict__ iw,
                         int* __restrict__ flagp){
  const int lane = threadIdx.x;
  unsigned w = xw[lane];
  int e0 = (int)((w >> 7) & 0xFF);
  int hit = (e0 >= 100 && e0 <= 134) ? 1 : 0;
  int zodd = ((lane & 1) && iw[lane] == 0u) ? 1 : 0;
#pragma unroll
  for (int s = 32; s >= 1; s >>= 1){
    hit  += __shfl_xor(hit,  s, 64);
    zodd += __shfl_xor(zodd, s, 64);
  }
  if (lane == 0){
    flagp[0] = (hit  >= 40) ? 1 : 0;
    flagp[1] = (zodd >= 24) ? 1 : 0;
  }
}

__global__ void ksent(float* __restrict__ out, int n, float c){
  int i = blockIdx.x*256 + threadIdx.x;
  if (i < n) out[i] = c;
}

// ---------- input conversion ----------
__global__ void kcvt_x(const void* __restrict__ lx, const void* __restrict__ rx,
                       const int* __restrict__ flagp, float* __restrict__ xall){
  const int flag = flagp[0];
  const int idx = blockIdx.x*256 + threadIdx.x;
  const void* src; int local;
  if (idx < NLIG*64){ src = lx; local = idx; } else { src = rx; local = idx - NLIG*64; }
  float v;
  if (flag) v = us2f(((const ushort_t*)src)[local]);
  else      v = ((const float*)src)[local];
  xall[idx] = v;
}

struct Srcs { const void* p[20]; };
__global__ void kcvt_w(Srcs S, const int* __restrict__ flagp, float* __restrict__ wcvt){
  const int bounds[21] = {0,4096,4160,5184,5248,267392,271488,275584,275648,283840,
                          283904,288000,292096,296192,300288,304384,308480,308544,308608,308672,308736};
  const int flag = flagp[0];
  const int idx = blockIdx.x*256 + threadIdx.x;
  if (idx >= 308736) return;
  int seg = 0;
#pragma unroll
  for (int s = 1; s < 20; ++s) if (idx >= bounds[s]) seg = s;
  const void* src = S.p[0];
#pragma unroll
  for (int s = 1; s < 20; ++s) if (seg == s) src = S.p[s];
  const int local = idx - bounds[seg];
  float v;
  if (flag) v = us2f(((const ushort_t*)src)[local]);
  else      v = ((const float*)src)[local];
  wcvt[idx] = v;
}

#define W_W0    0
#define W_B0    4096
#define W_WE1   4160
#define W_BE1   5184
#define W_WE2   5248
#define W_BE2   267392
#define W_RESW  271488
#define W_CONVB 275584
#define W_MSGW  275648
#define W_MSGB  283840
#define W_QLIG  283904
#define W_KLIG  288000
#define W_VLIG  292096
#define W_QREC  296192
#define W_KREC  300288
#define W_VREC  304384
#define W_GLIG  308480
#define W_BLIG  308544
#define W_GREC  308608
#define W_BREC  308672

// Fragment-packed We2: Wpk[((kb*4+t)*2+p)*512 + lane*8 + j]
__global__ void kWpk(const float* __restrict__ We2f, ushort_t* __restrict__ Wpk){
  int oidx = blockIdx.x*256 + threadIdx.x;   // 524288 exact (grid 2048)
  int j = oidx & 7, lane = (oidx >> 3) & 63, p = (oidx >> 9) & 1;
  int t = (oidx >> 10) & 3, kb = oidx >> 12;
  int o = t*16 + (lane & 15);
  int gik = kb*32 + (lane >> 4)*8 + j;
  int i = gik >> 6, k = gik & 63;
  float v = We2f[(size_t)(i*64 + o)*64 + k];
  ushort_t hi = f2us(v);
  Wpk[oidx] = p ? f2us(v - us2f(hi)) : hi;
}

// h0 = relu(x @ W0^T + b0), f32
__global__ void kh0(const float* __restrict__ xall, const float* __restrict__ W0f,
                    const float* __restrict__ b0f, float* __restrict__ h){
  __shared__ float xr[4][64];
  const int lane = threadIdx.x & 63, wv = threadIdx.x >> 6;
  const int n = blockIdx.x*4 + wv;
  xr[wv][lane] = xall[(size_t)n*64 + lane];
  __syncthreads();
  float acc = b0f[lane];
  const float* wr = W0f + lane*64;
#pragma unroll
  for (int i = 0; i < 64; ++i) acc += xr[wv][i] * wr[i];
  h[(size_t)n*64 + lane] = acc > 0.f ? acc : 0.f;
}

__global__ void khist(const int* __restrict__ ldst, const int* __restrict__ rdst,
                      const int* __restrict__ flagp, int* __restrict__ counts){
  const int i64 = flagp[1];
  const int e = blockIdx.x*256 + threadIdx.x;
  if (e >= ETOT) return;
  int dstg = (e < ELIG) ? geti(ldst, e, i64) : geti(rdst, e - ELIG, i64) + NLIG;
  atomicAdd(&counts[dstg], 1);
}

__global__ __launch_bounds__(1024) void kscan(const int* __restrict__ counts, int* __restrict__ offs){
  __shared__ int part[1024];
  const int tid = threadIdx.x;
  const int PER = 20;
  int loc[PER]; int s = 0;
#pragma unroll
  for (int j = 0; j < PER; ++j){ int idx = tid*PER + j; int v = (idx < NTOT) ? counts[idx] : 0; loc[j] = s; s += v; }
  part[tid] = s;
  __syncthreads();
  for (int d = 1; d < 1024; d <<= 1){
    int add = (tid >= d) ? part[tid - d] : 0;
    __syncthreads();
    part[tid] += add;
    __syncthreads();
  }
  int pre = (tid > 0) ? part[tid - 1] : 0;
#pragma unroll
  for (int j = 0; j < PER; ++j){ int idx = tid*PER + j; if (idx < NTOT) offs[idx] = pre + loc[j]; }
  if (tid == 1023) offs[NTOT] = part[1023];
}

__global__ void kfill(const int* __restrict__ lsrc, const int* __restrict__ ldst,
                      const int* __restrict__ rsrc, const int* __restrict__ rdst,
                      const void* __restrict__ lef, const void* __restrict__ ref_,
                      const int* __restrict__ offs, int* __restrict__ cursor,
                      const int* __restrict__ flagp,
                      int* __restrict__ e_srcn, float* __restrict__ ef_srt){
  const int flag = flagp[0];
  const int i64  = flagp[1];
  const int e = blockIdx.x*256 + threadIdx.x;
  if (e >= ETOT) return;
  int srcg, dstg, le; const void* efb;
  if (e < ELIG){ srcg = geti(lsrc, e, i64); dstg = geti(ldst, e, i64); efb = lef; le = e; }
  else {
    int e2 = e - ELIG;
    srcg = geti(rsrc, e2, i64) + NLIG; dstg = geti(rdst, e2, i64) + NLIG; efb = ref_; le = e2;
  }
  int pos = offs[dstg] + atomicAdd(&cursor[dstg], 1);
  e_srcn[pos] = srcg;
  float* efd = ef_srt + (size_t)pos*16;
  if (flag){
    const ushort_t* efp = (const ushort_t*)efb + (size_t)le*16;
#pragma unroll
    for (int c = 0; c < 16; ++c) efd[c] = us2f(efp[c]);
  } else {
    const float* efp = (const float*)efb + (size_t)le*16;
#pragma unroll
    for (int c = 0; c < 16; ++c) efd[c] = efp[c];
  }
}

// z_srt[e][64] = relu(ef_srt[e] @ We1^T + be1), f32 — step-invariant, computed once.
// Summation order identical to old per-step recompute (bit-identical results).
__global__ void kz(const float* __restrict__ ef_srt, const float* __restrict__ We1f,
                   const float* __restrict__ be1f, float* __restrict__ z_srt){
  const int lane = threadIdx.x & 63, wv = threadIdx.x >> 6;
  const int e = blockIdx.x*4 + wv;           // grid = ETOT/4 exact
  const float* efp = ef_srt + (size_t)e*16;
  float acc = be1f[lane];
  const float* wr = We1f + lane*16;
#pragma unroll
  for (int c = 0; c < 16; ++c) acc += efp[c] * wr[c];
  z_srt[(size_t)e*64 + lane] = acc > 0.f ? acc : 0.f;
}

// ---------- fused message-passing step: 16 nodes/WG, 16 waves, packed-B MFMA ----------
#define SROW 2080
#define SLO  (16*SROW)
__global__ __launch_bounds__(1024)
void kstep(const float* __restrict__ hin, float* __restrict__ hout,
           const int* __restrict__ offs, const int* __restrict__ e_srcn,
           const float* __restrict__ z_srt,
           const ushort_t* __restrict__ Wpk,
           const float* __restrict__ resWf, const float* __restrict__ convbf,
           const float* __restrict__ msgWf, const float* __restrict__ msgbf,
           const float* __restrict__ be2f){
  __shared__ alignas(16) char sbuf[2*SLO];   // 66560 B; epilogue overlays
  __shared__ float h_lds[1024];
  __shared__ float Hs_lds[1024];
  __shared__ float m_lds[1024];
  __shared__ float cbf[64], mbf[64];

  const int tid = threadIdx.x, lane = tid & 63, wv = tid >> 6;
  const int n0 = blockIdx.x * 16;            // grid = NTOT/16 = 1250 exact

  h_lds[tid] = hin[(size_t)n0*64 + tid];
  if (tid < 64){ cbf[tid] = convbf[tid]; mbf[tid] = msgbf[tid]; }

  // phase 1: node v = n0+wv; lane owns z-dim k=lane; sacc[i] = S_v[i][lane]
  float sacc[64];
#pragma unroll
  for (int i = 0; i < 64; ++i) sacc[i] = 0.f;
  float hs = 0.f;
  {
    const int v = n0 + wv;
    const int jb = offs[v], je = offs[v+1];
    for (int j = jb; j < je; ++j){
      const int sn = e_srcn[j];
      const float zl = z_srt[(size_t)j*64 + lane];
      hs += hin[(size_t)sn*64 + lane];
      const float4* hp = (const float4*)(hin + (size_t)sn*64);
#pragma unroll
      for (int i4 = 0; i4 < 16; ++i4){
        float4 hv = hp[i4];
        sacc[i4*4+0] += hv.x * zl;
        sacc[i4*4+1] += hv.y * zl;
        sacc[i4*4+2] += hv.z * zl;
        sacc[i4*4+3] += hv.w * zl;
      }
    }
    Hs_lds[wv*64 + lane] = hs;
  }

  // phase 2
  const int r15 = lane & 15, g4 = lane >> 4;
  const int tW = wv & 3, kq = wv >> 2;
  f32x4 acc; acc[0]=0.f; acc[1]=0.f; acc[2]=0.f; acc[3]=0.f;
#pragma unroll
  for (int c = 0; c < 4; ++c){
#pragma unroll
    for (int ii = 0; ii < 16; ++ii){
      float v = sacc[c*16 + ii];
      ushort_t hi16 = f2us(v);
      unsigned off = (unsigned)(wv*SROW + (ii*64 + lane)*2);
      *(ushort_t*)(sbuf + off) = hi16;
      *(ushort_t*)(sbuf + SLO + off) = f2us(v - us2f(hi16));
    }
    __syncthreads();
    for (int kk = 0; kk < 8; ++kk){
      const int lk = kq*256 + kk*32;
      const int kb = c*32 + kq*8 + kk;
      const unsigned aoff = (unsigned)(r15*SROW + (lk + g4*8)*2);
      const short8_t ah = *(const short8_t*)(sbuf + aoff);
      const short8_t al = *(const short8_t*)(sbuf + SLO + aoff);
      const ushort_t* bp = Wpk + (size_t)(kb*4 + tW)*1024 + lane*8;
      const short8_t bh = *(const short8_t*)(bp);
      const short8_t bl = *(const short8_t*)(bp + 512);
      acc = mfma32(ah, bh, acc);
      acc = mfma32(ah, bl, acc);
      acc = mfma32(al, bh, acc);
    }
    __syncthreads();
  }

  // epilogue
  float* redf  = (float*)sbuf;
  float* be2s  = (float*)(sbuf + 16384);
  float* resWt = (float*)(sbuf + 32768);
#pragma unroll
  for (int q = 0; q < 4; ++q)
    redf[kq*1024 + (g4*4 + q)*64 + tW*16 + r15] = acc[q];
  for (int idx = tid; idx < 4096; idx += 1024){
    be2s[idx] = be2f[idx];
    resWt[(idx & 63)*65 + (idx >> 6)] = resWf[idx];
  }
  __syncthreads();
  {
    float aggv = cbf[lane];
#pragma unroll
    for (int k4 = 0; k4 < 4; ++k4) aggv += redf[k4*1024 + wv*64 + lane];
    float t1 = 0.f, t2 = 0.f;
#pragma unroll 8
    for (int i = 0; i < 64; ++i){
      t1 += Hs_lds[wv*64 + i] * be2s[i*64 + lane];
      t2 += h_lds[wv*64 + i]  * resWt[i*65 + lane];
    }
    float mv = aggv + t1 + t2;
    m_lds[wv*64 + lane] = mv > 0.f ? mv : 0.f;
  }
  __syncthreads();
  float* msgWt = (float*)sbuf;
  for (int idx = tid; idx < 8192; idx += 1024)
    msgWt[(idx & 127)*65 + (idx >> 7)] = msgWf[idx];
  __syncthreads();
  {
    float hn = mbf[lane];
#pragma unroll 8
    for (int i = 0; i < 64; ++i){
      hn += m_lds[wv*64 + i] * msgWt[i*65 + lane];
      hn += h_lds[wv*64 + i] * msgWt[(64 + i)*65 + lane];
    }
    hout[(size_t)(n0 + wv)*64 + lane] = hn;
  }
}

// ---------- Fv residual + mid-LN + q/k/v projections (q,k hi/lo bf16; V transposed) ----------
__global__ void kfvproj(const float* __restrict__ h, const float* __restrict__ xall,
    const float* __restrict__ wcvt,
    ushort_t* __restrict__ qbh, ushort_t* __restrict__ qbl,
    ushort_t* __restrict__ kbh, ushort_t* __restrict__ kbl,
    ushort_t* __restrict__ vbT){
  __shared__ float hr[4][64];
  const int lane = threadIdx.x & 63, wv = threadIdx.x >> 6;
  const int n = blockIdx.x*4 + wv;
  const bool isLig = n < NLIG;
  const float fv = h[(size_t)n*64 + lane] + xall[(size_t)n*64 + lane];
  const float mu = wsum64(fv) * (1.f/64.f);
  const float dd = fv - mu;
  const float var = wsum64(dd*dd) * (1.f/64.f);
  const float gg = wcvt[(isLig ? W_GLIG : W_GREC) + lane];
  const float bb = wcvt[(isLig ? W_BLIG : W_BREC) + lane];
  const float hl = dd * rsqrtf(var + 1e-5f) * gg + bb;
  hr[wv][lane] = hl;
  __syncthreads();
  const float* Qw = wcvt + (isLig ? W_QLIG : W_QREC) + lane*64;
  const float* Kw = wcvt + (isLig ? W_KLIG : W_KREC) + lane*64;
  const float* Vw = wcvt + (isLig ? W_VLIG : W_VREC) + lane*64;
  float qa = 0.f, ka = 0.f, va = 0.f;
#pragma unroll
  for (int i = 0; i < 64; ++i){
    const float hv = hr[wv][i];
    qa += hv * Qw[i];
    ka += hv * Kw[i];
    va += hv * Vw[i];
  }
  qa = qa > 0.f ? qa : 0.01f*qa;
  ka = ka > 0.f ? ka : 0.01f*ka;
  const size_t o = (size_t)n*64 + lane;
  ushort_t qh = f2us(qa); qbh[o] = qh; qbl[o] = f2us(qa - us2f(qh));
  ushort_t kh = f2us(ka); kbh[o] = kh; kbl[o] = f2us(ka - us2f(kh));
  vbT[(size_t)lane*VSTRIDE + n] = f2us(va);
}

// ---------- merged masked cross-attention + final LN (both directions, one dispatch) ----------
// Round-12 proven version: TILE=256, 1-deep prefetch, 35KB LDS, 43% occupancy.
__global__ __launch_bounds__(512)
void kattn2(const ushort_t* __restrict__ qbh, const ushort_t* __restrict__ qbl,
            const ushort_t* __restrict__ kbh, const ushort_t* __restrict__ kbl,
            const ushort_t* __restrict__ vbT, const void* __restrict__ maskp,
            const int* __restrict__ flagp, const float* __restrict__ wcvt,
            float* __restrict__ out){
  __shared__ alignas(16) char abuf[34816];   // union: m_tile[2][16][257] f32 | ored[8][64][17] f32
  __shared__ float mred[8][16], lred[8][16];
  float (*m_tile)[16][257] = (float(*)[16][257])abuf;
  float (*ored)[64][17]    = (float(*)[64][17])abuf;

  const int flag = flagp[0];
  const int bx = blockIdx.x;
  const int dirn = (bx < NB0) ? 0 : 1;
  const int bid  = dirn ? (bx - NB0) : bx;
  const int R   = dirn ? NREC : NLIG;
  const int C   = dirn ? NLIG : NREC;
  const int RNB = dirn ? NLIG : 0;
  const int CNB = dirn ? 0 : NLIG;
  const float* gwf = wcvt + (dirn ? W_GREC : W_GLIG);
  const float* bwf = wcvt + (dirn ? W_BREC : W_BLIG);
  float* outp = out + (size_t)RNB*64;

  const int tid = threadIdx.x, lane = tid & 63, wv = tid >> 6;
  const int r15 = lane & 15, g4 = lane >> 4;
  const int rbase = bid * 16;
  int rn = rbase + r15; if (rn > R-1) rn = R-1;

  const ushort_t* qph = qbh + (size_t)(RNB + rn)*64;
  const ushort_t* qpl = qbl + (size_t)(RNB + rn)*64;
  const short8_t qh0a = *(const short8_t*)(qph + g4*8);
  const short8_t qh0b = *(const short8_t*)(qph + 32 + g4*8);
  const short8_t ql0a = *(const short8_t*)(qpl + g4*8);
  const short8_t ql0b = *(const short8_t*)(qpl + 32 + g4*8);

  const int srcA = (((g4 & 1) * 2)     << 4) + r15;
  const int srcB = (((g4 & 1) * 2 + 1) << 4) + r15;
  const bool hiBank = (g4 >> 1) != 0;

  const int s_row = tid >> 5, s_l31 = tid & 31;      // dirn 0
  const int s_cl = tid >> 1, s_half = tid & 1;       // dirn 1

  float mr[8];
  auto load_tile = [&](int tb2){
    if (dirn == 0){
      int r = rbase + s_row; if (r > R-1) r = R-1;
      const size_t base = (size_t)r*NREC + tb2;
      const int cmax = C-1 - tb2;
      if (flag){
        const ushort_t* mp = (const ushort_t*)maskp + base;
#pragma unroll
        for (int j = 0; j < 8; ++j){
          int cj = s_l31 + 32*j; if (cj > cmax) cj = cmax;
          mr[j] = us2f(mp[cj]);
        }
      } else {
        const float* mp = (const float*)maskp + base;
#pragma unroll
        for (int j = 0; j < 8; ++j){
          int cj = s_l31 + 32*j; if (cj > cmax) cj = cmax;
          mr[j] = mp[cj];
        }
      }
    } else {
      int c = tb2 + s_cl; if (c > C-1) c = C-1;
      int r0 = rbase + s_half*8; if (r0 > R-8) r0 = R-8;
      const size_t base = (size_t)c*NREC + r0;
      if (flag){
        const ushort_t* mp = (const ushort_t*)maskp + base;
        const short8_t v8 = *(const short8_t*)mp;
#pragma unroll
        for (int j = 0; j < 8; ++j) mr[j] = us2f((ushort_t)v8[j]);
      } else {
        const float* mp = (const float*)maskp + base;
        const float4 v0 = *(const float4*)mp;
        const float4 v1 = *(const float4*)(mp + 4);
        mr[0]=v0.x; mr[1]=v0.y; mr[2]=v0.z; mr[3]=v0.w;
        mr[4]=v1.x; mr[5]=v1.y; mr[6]=v1.z; mr[7]=v1.w;
      }
    }
  };

  float mrun = -1e30f, lrun = 0.f;
  f32x4 oacc[4];
#pragma unroll
  for (int t = 0; t < 4; ++t){ oacc[t][0]=0.f; oacc[t][1]=0.f; oacc[t][2]=0.f; oacc[t][3]=0.f; }

  load_tile(0);
  int buf = 0;
  for (int tb = 0; tb < C; tb += 256){
    if (dirn == 0){
#pragma unroll
      for (int j = 0; j < 8; ++j) m_tile[buf][s_row][s_l31 + 32*j] = mr[j];
    } else {
#pragma unroll
      for (int j = 0; j < 8; ++j) m_tile[buf][s_half*8 + j][s_cl] = mr[j];
    }
    if (tb + 256 < C) load_tile(tb + 256);
    __syncthreads();

    const int cb = tb + wv*32;
    int cn0 = cb + r15;      if (cn0 > C-1) cn0 = C-1;
    int cn1 = cb + 16 + r15; if (cn1 > C-1) cn1 = C-1;
    const ushort_t* kp0h = kbh + (size_t)(CNB + cn0)*64;
    const ushort_t* kp0l = kbl + (size_t)(CNB + cn0)*64;
    const ushort_t* kp1h = kbh + (size_t)(CNB + cn1)*64;
    const ushort_t* kp1l = kbl + (size_t)(CNB + cn1)*64;
    f32x4 st0; st0[0]=0.f; st0[1]=0.f; st0[2]=0.f; st0[3]=0.f;
    f32x4 st1 = st0;
    {
      short8_t ka_ = *(const short8_t*)(kp0h + g4*8);
      short8_t kb_ = *(const short8_t*)(kp0h + 32 + g4*8);
      st0 = mfma32(ka_, qh0a, st0); st0 = mfma32(kb_, qh0b, st0);
      st0 = mfma32(ka_, ql0a, st0); st0 = mfma32(kb_, ql0b, st0);
      short8_t kc_ = *(const short8_t*)(kp0l + g4*8);
      short8_t kd_ = *(const short8_t*)(kp0l + 32 + g4*8);
      st0 = mfma32(kc_, qh0a, st0); st0 = mfma32(kd_, qh0b, st0);
    }
    {
      short8_t ka_ = *(const short8_t*)(kp1h + g4*8);
      short8_t kb_ = *(const short8_t*)(kp1h + 32 + g4*8);
      st1 = mfma32(ka_, qh0a, st1); st1 = mfma32(kb_, qh0b, st1);
      st1 = mfma32(ka_, ql0a, st1); st1 = mfma32(kb_, ql0b, st1);
      short8_t kc_ = *(const short8_t*)(kp1l + g4*8);
      short8_t kd_ = *(const short8_t*)(kp1l + 32 + g4*8);
      st1 = mfma32(kc_, qh0a, st1); st1 = mfma32(kd_, qh0b, st1);
    }
    float sv0[4], sv1[4]; float tmax = -1e30f;
#pragma unroll
    for (int j = 0; j < 4; ++j){
      const int c0 = cb + g4*4 + j, c1 = cb + 16 + g4*4 + j;
      const float mv0 = m_tile[buf][r15][wv*32 + g4*4 + j];
      const float mv1 = m_tile[buf][r15][wv*32 + 16 + g4*4 + j];
      sv0[j] = (c0 < C) ? mv0 * (st0[j] + 1000.f) : -1e30f;
      sv1[j] = (c1 < C) ? mv1 * (st1[j] + 1000.f) : -1e30f;
      tmax = fmaxf(tmax, fmaxf(sv0[j], sv1[j]));
    }
    tmax = fmaxf(tmax, __shfl_xor(tmax, 16, 64));
    tmax = fmaxf(tmax, __shfl_xor(tmax, 32, 64));
    const float mnew = fmaxf(mrun, tmax);
    const float corr = __expf(mrun - mnew);
    float ps0[4], ps1[4], psum = 0.f;
#pragma unroll
    for (int j = 0; j < 4; ++j){
      ps0[j] = __expf(sv0[j] - mnew); psum += ps0[j];
      ps1[j] = __expf(sv1[j] - mnew); psum += ps1[j];
    }
    psum += __shfl_xor(psum, 16, 64);
    psum += __shfl_xor(psum, 32, 64);
    lrun = lrun * corr + psum;
    mrun = mnew;
    const unsigned pk0 = pkbf(ps0[0], ps0[1]);
    const unsigned pk1 = pkbf(ps0[2], ps0[3]);
    const unsigned pk2 = pkbf(ps1[0], ps1[1]);
    const unsigned pk3 = pkbf(ps1[2], ps1[3]);
    const unsigned a0 = (unsigned)__shfl((int)pk0, srcA, 64);
    const unsigned a2 = (unsigned)__shfl((int)pk2, srcA, 64);
    const unsigned a1 = (unsigned)__shfl((int)pk1, srcA, 64);
    const unsigned a3 = (unsigned)__shfl((int)pk3, srcA, 64);
    const unsigned b0 = (unsigned)__shfl((int)pk0, srcB, 64);
    const unsigned b2 = (unsigned)__shfl((int)pk2, srcB, 64);
    const unsigned b1 = (unsigned)__shfl((int)pk1, srcB, 64);
    const unsigned b3 = (unsigned)__shfl((int)pk3, srcB, 64);
    uint4_t pw;
    pw[0] = hiBank ? a2 : a0;
    pw[1] = hiBank ? a3 : a1;
    pw[2] = hiBank ? b2 : b0;
    pw[3] = hiBank ? b3 : b1;
    const short8_t pf8 = *reinterpret_cast<const short8_t*>(&pw);
    const ushort_t* vtb = vbT + (size_t)(CNB + cb + g4*8);
#pragma unroll
    for (int t = 0; t < 4; ++t){
#pragma unroll
      for (int q = 0; q < 4; ++q) oacc[t][q] *= corr;
      const short8_t af = *(const short8_t*)(vtb + (size_t)(t*16 + r15)*VSTRIDE);
      oacc[t] = mfma32(af, pf8, oacc[t]);
    }
    buf ^= 1;
  }

  __syncthreads();   // all m_tile reads done before ored overlay writes
  if (g4 == 0){ mred[wv][r15] = mrun; lred[wv][r15] = lrun; }
#pragma unroll
  for (int t = 0; t < 4; ++t)
#pragma unroll
    for (int q = 0; q < 4; ++q)
      ored[wv][t*16 + g4*4 + q][r15] = oacc[t][q];
  __syncthreads();

  for (int rr = 2*wv; rr <= 2*wv + 1; ++rr){
    float mstar = -1e30f;
#pragma unroll
    for (int w = 0; w < 8; ++w) mstar = fmaxf(mstar, mred[w][rr]);
    float lstar = 0.f, ov = 0.f;
#pragma unroll
    for (int w = 0; w < 8; ++w){
      const float e = __expf(mred[w][rr] - mstar);
      lstar += lred[w][rr] * e;
      ov    += ored[w][lane][rr] * e;
    }
    const float att = ov / lstar;
    const float mu = wsum64(att) * (1.f/64.f);
    const float dd = att - mu;
    const float var = wsum64(dd*dd) * (1.f/64.f);
    const float y = dd * rsqrtf(var + 1e-5f) * gwf[lane] + bwf[lane];
    const int rg = rbase + rr;
    if (rg < R) outp[(size_t)rg*64 + lane] = y;
  }
}

// ---------- host ----------
extern "C" void kernel_launch(void* const* d_in, const int* in_sizes, int n_in,
                              void* d_out, int out_size, void* d_ws, size_t ws_size,
                              hipStream_t stream){
  const int expsz[29] = {320000,800000,50000,50000,960000,2400000,150000,150000,75000000,
                         4096,64,1024,64,262144,4096,4096,64,8192,64,
                         4096,4096,4096,4096,4096,4096,64,64,64,64};
  bool ok = (n_in == 29);
  if (ok) for (int i = 0; i < 29; ++i) if (in_sizes[i] != expsz[i]) ok = false;
  if (!ok){
    ksent<<<(out_size + 255)/256, 256, 0, stream>>>((float*)d_out, out_size, 10.0f);
    return;
  }

  const void* lig_n = d_in[0];
  const void* lig_e = d_in[1];
  const int* lig_src = (const int*)d_in[2];
  const int* lig_dst = (const int*)d_in[3];
  const void* rec_n = d_in[4];
  const void* rec_e = d_in[5];
  const int* rec_src = (const int*)d_in[6];
  const int* rec_dst = (const int*)d_in[7];
  const void* mask = d_in[8];

  char* p = (char*)d_ws;
  auto carve = [&](size_t bytes)->char*{ char* r = p; p += (bytes + 255) & ~(size_t)255; return r; };
  float*    xall  = (float*)   carve((size_t)NTOT*64*4);
  float*    wcvt  = (float*)   carve((size_t)308736*4);
  float*    h_a   = (float*)   carve((size_t)NTOT*64*4);
  float*    h_b   = (float*)   carve((size_t)NTOT*64*4);
  ushort_t* Wpk   = (ushort_t*)carve((size_t)524288*2);
  ushort_t* qbh   = (ushort_t*)carve((size_t)NTOT*64*2);
  ushort_t* qbl   = (ushort_t*)carve((size_t)NTOT*64*2);
  ushort_t* kbh   = (ushort_t*)carve((size_t)NTOT*64*2);
  ushort_t* kbl   = (ushort_t*)carve((size_t)NTOT*64*2);
  ushort_t* vbT   = (ushort_t*)carve((size_t)64*VSTRIDE*2);
  int*      flag  = (int*)     carve(256);
  int*      counts= (int*)     carve((size_t)2*NTOT*4);
  int*      cursor= counts + NTOT;
  int*      offs  = (int*)     carve((size_t)(NTOT+1)*4);
  int*      e_srcn= (int*)     carve((size_t)ETOT*4);
  float*    ef_srt= (float*)   carve((size_t)ETOT*16*4);
  float*    z_srt = (float*)   carve((size_t)ETOT*64*4);

  if ((size_t)(p - (char*)d_ws) > ws_size){
    ksent<<<(out_size + 255)/256, 256, 0, stream>>>((float*)d_out, out_size, 20.0f);
    return;
  }

  Srcs S;
  for (int i = 0; i < 20; ++i) S.p[i] = d_in[9 + i];

  hipMemsetAsync(counts, 0, (size_t)2*NTOT*4, stream);
  hipMemsetAsync(vbT, 0, (size_t)64*VSTRIDE*2, stream);
  kdetect2<<<1, 64, 0, stream>>>((const unsigned*)lig_n, (const unsigned*)lig_src, flag);
  kcvt_x<<<NTOT*64/256, 256, 0, stream>>>(lig_n, rec_n, flag, xall);
  kcvt_w<<<(308736 + 255)/256, 256, 0, stream>>>(S, flag, wcvt);
  kWpk<<<2048, 256, 0, stream>>>(wcvt + W_WE2, Wpk);
  kh0<<<NTOT/4, 256, 0, stream>>>(xall, wcvt + W_W0, wcvt + W_B0, h_a);
  khist<<<(ETOT + 255)/256, 256, 0, stream>>>(lig_dst, rec_dst, flag, counts);
  kscan<<<1, 1024, 0, stream>>>(counts, offs);
  kfill<<<(ETOT + 255)/256, 256, 0, stream>>>(lig_src, lig_dst, rec_src, rec_dst,
                                              lig_e, rec_e, offs, cursor, flag, e_srcn, ef_srt);
  kz<<<ETOT/4, 256, 0, stream>>>(ef_srt, wcvt + W_WE1, wcvt + W_BE1, z_srt);
  float* hi = h_a; float* ho = h_b;
  for (int s = 0; s < 6; ++s){
    kstep<<<NTOT/16, 1024, 0, stream>>>(hi, ho, offs, e_srcn, z_srt, Wpk,
                                        wcvt + W_RESW, wcvt + W_CONVB,
                                        wcvt + W_MSGW, wcvt + W_MSGB, wcvt + W_BE2);
    float* t = hi; hi = ho; ho = t;
  }
  kfvproj<<<NTOT/4, 256, 0, stream>>>(hi, xall, wcvt, qbh, qbl, kbh, kbl, vbT);
  kattn2<<<NB0 + NB1, 512, 0, stream>>>(qbh, qbl, kbh, kbl, vbT, mask, flag, wcvt,
                                        (float*)d_out);
}